// Round 21
// baseline (286.759 us; speedup 1.0000x reference)
//
#include <hip/hip_runtime.h>
#include <float.h>

// VectorQuantize: h=8 heads, c=2048 codes, d=64, b=8, t=2048 (n=16384 vec/head)
#define H   8
#define C   2048
#define D   64
#define NPH 16384     // vectors per head (b*t)
#define HD  512       // h*d
#define DECAYF 0.9f
#define DELTA 3.0f    // candidate margin >= 2x worst-case bf16 score error (~0.6)
#define CAP 64        // per-vector candidate slots
#define VB  256       // vectors per block (512 blocks)

typedef __attribute__((ext_vector_type(8))) short short8v;   // 8 bf16 (4 VGPR)
typedef __attribute__((ext_vector_type(4))) float f32x4;

__device__ inline unsigned short f32_to_bf16_rne(float f) {
    unsigned int x = __float_as_uint(f);
    return (unsigned short)((x + 0x7FFFu + ((x >> 16) & 1u)) >> 16);
}

// ---------------------------------------------------------------------------
// Kernel 0: fused prep. Thread = one codebook row r = (h, ch*16+c):
//   esq[r] = serial-fmaf sum of squares; keb2 = bf16 codebook PRE-SWIZZLED
//   into MFMA-fragment-linear order (R15 win); counts[r] = 0.
// ---------------------------------------------------------------------------
__global__ __launch_bounds__(256) void vq_prep_kernel(const float* __restrict__ ke,
                                                      unsigned short* __restrict__ keb2,
                                                      float* __restrict__ esq,
                                                      unsigned int* __restrict__ counts) {
    const int row = blockIdx.x * 256 + threadIdx.x;   // 0 .. H*C-1
    const int c   = row & 15;
    const int ch  = (row >> 4) & 127;
    const int h   = row >> 11;
    const float* e = ke + (size_t)row * D;
    unsigned short* kb = keb2 + ((size_t)h * C * D) + (size_t)ch * 1024;
#pragma unroll
    for (int kf = 0; kf < 2; ++kf)
#pragma unroll
        for (int g = 0; g < 4; ++g) {
            float4 v0 = ((const float4*)e)[kf * 8 + g * 2];
            float4 v1 = ((const float4*)e)[kf * 8 + g * 2 + 1];
            short8v o;
            o[0] = (short)f32_to_bf16_rne(v0.x); o[1] = (short)f32_to_bf16_rne(v0.y);
            o[2] = (short)f32_to_bf16_rne(v0.z); o[3] = (short)f32_to_bf16_rne(v0.w);
            o[4] = (short)f32_to_bf16_rne(v1.x); o[5] = (short)f32_to_bf16_rne(v1.y);
            o[6] = (short)f32_to_bf16_rne(v1.z); o[7] = (short)f32_to_bf16_rne(v1.w);
            *(short8v*)(kb + kf * 512 + (g * 16 + c) * 8) = o;
        }
    float s = 0.f;
#pragma unroll
    for (int d = 0; d < D; ++d) s = fmaf(e[d], e[d], s);
    esq[row] = s;
    counts[row] = 0u;
}

// ---------------------------------------------------------------------------
// Kernel 1: SINGLE-PASS MFMA screening + exact rescore.
//   R21 vs R20: one scan instead of two. Collect when sc <= running_min +
//   DELTA. Superset guarantee: running_min >= final_min at all times, so
//   the collected set contains the two-pass set, which contains the true
//   argmin (sc* <= final_min + 2eps <= running_min + DELTA, DELTA=3 >= 2eps
//   ~0.6). Set is iteration-order-deterministic; rescore min is order-
//   independent; CAP overflow -> deterministic per-vector full exact scan.
//   Warm-up: 8 chunks min-only + cross-lane SYNC (tight thresholds);
//   re-SYNC every 32 chunks caps candidate inflation. Warm-up chunks are
//   recomputed in the scan (+6% MFMA) vs -47% total chunk-instances.
//   R14's single-pass regression predates the swizzled-B layout (R15), CAP
//   64 (vs 96/52KB LDS), and paired-chunk batching (R20) -- all confounds
//   removed. Per-chunk score chains bit-identical to passing R15-R20.
// ---------------------------------------------------------------------------
__global__ __launch_bounds__(256, 2)
void vq_main_kernel(const float* __restrict__ x,
                    const unsigned short* __restrict__ keb2,
                    const float* __restrict__ ke,
                    const float* __restrict__ esq,
                    float* __restrict__ outq,
                    float* __restrict__ outi,
                    unsigned short* __restrict__ indw,
                    unsigned int* __restrict__ counts) {
    __shared__ int            ccnt[VB];
    __shared__ unsigned short cand[VB][CAP];
    __shared__ int            sidx[VB];

    const int tid  = threadIdx.x;
    const int lane = tid & 63;
    const int w    = __builtin_amdgcn_readfirstlane(tid >> 6);
    const int h    = blockIdx.x & 7;
    const int n0   = (blockIdx.x >> 3) * VB;

    const unsigned short* keb2h = keb2 + (size_t)h * C * D;
    const float* keh  = ke  + (size_t)h * C * D;
    const float* esqh = esq + (size_t)h * C;

    ccnt[tid] = 0;
    __syncthreads();

    const int col = lane & 15;        // code col within 16-tile
    const int kg  = (lane >> 4) * 8;  // this lane's k-group base

    // ---- A-frags: lane's 4 vec-rows x 64 k, bf16, persistent ----
    short8v afr[4][2];
#pragma unroll
    for (int vt = 0; vt < 4; ++vt) {
        const float* xp = x + (size_t)(n0 + w * 64 + vt * 16 + col) * HD
                            + (size_t)h * D + kg;
#pragma unroll
        for (int kf = 0; kf < 2; ++kf) {
            float4 u0 = *(const float4*)(xp + kf * 32);
            float4 u1 = *(const float4*)(xp + kf * 32 + 4);
            short8v a;
            a[0] = (short)f32_to_bf16_rne(u0.x); a[1] = (short)f32_to_bf16_rne(u0.y);
            a[2] = (short)f32_to_bf16_rne(u0.z); a[3] = (short)f32_to_bf16_rne(u0.w);
            a[4] = (short)f32_to_bf16_rne(u1.x); a[5] = (short)f32_to_bf16_rne(u1.y);
            a[6] = (short)f32_to_bf16_rne(u1.z); a[7] = (short)f32_to_bf16_rne(u1.w);
            afr[vt][kf] = a;
        }
    }

    float amin[16];
#pragma unroll
    for (int s = 0; s < 16; ++s) amin[s] = FLT_MAX;

    // coalesced fragment load: B0 = kb[lane], B1 = kb[64+lane]
#define LOADB2(CH, B0, B1, EQ)                                                 \
    {                                                                          \
        const short8v* kb = (const short8v*)(keb2h + (size_t)(CH) * 1024);     \
        B0 = kb[lane];                                                         \
        B1 = kb[64 + lane];                                                    \
        EQ = esqh[((CH) << 4) + col];                                          \
    }

    // MFMA one chunk into 4 named accs (vt = 0..3)
#define MFMA4(C0V, C1V, A0, A1, A2, A3)                                        \
    {                                                                          \
        A0 = (f32x4){0.f, 0.f, 0.f, 0.f};                                      \
        A1 = (f32x4){0.f, 0.f, 0.f, 0.f};                                      \
        A2 = (f32x4){0.f, 0.f, 0.f, 0.f};                                      \
        A3 = (f32x4){0.f, 0.f, 0.f, 0.f};                                      \
        A0 = __builtin_amdgcn_mfma_f32_16x16x32_bf16(afr[0][0], C0V, A0, 0, 0, 0); \
        A1 = __builtin_amdgcn_mfma_f32_16x16x32_bf16(afr[1][0], C0V, A1, 0, 0, 0); \
        A2 = __builtin_amdgcn_mfma_f32_16x16x32_bf16(afr[2][0], C0V, A2, 0, 0, 0); \
        A3 = __builtin_amdgcn_mfma_f32_16x16x32_bf16(afr[3][0], C0V, A3, 0, 0, 0); \
        A0 = __builtin_amdgcn_mfma_f32_16x16x32_bf16(afr[0][1], C1V, A0, 0, 0, 0); \
        A1 = __builtin_amdgcn_mfma_f32_16x16x32_bf16(afr[1][1], C1V, A1, 0, 0, 0); \
        A2 = __builtin_amdgcn_mfma_f32_16x16x32_bf16(afr[2][1], C1V, A2, 0, 0, 0); \
        A3 = __builtin_amdgcn_mfma_f32_16x16x32_bf16(afr[3][1], C1V, A3, 0, 0, 0); \
    }

    // min-only epilogue (warm-up)
#define EPI1(A0, A1, A2, A3, QV)                                               \
    {                                                                          \
        _Pragma("unroll")                                                      \
        for (int r = 0; r < 4; ++r) {                                          \
            amin[0 + r]  = fminf(amin[0 + r],  fmaf(-2.f, A0[r], QV));         \
            amin[4 + r]  = fminf(amin[4 + r],  fmaf(-2.f, A1[r], QV));         \
            amin[8 + r]  = fminf(amin[8 + r],  fmaf(-2.f, A2[r], QV));         \
            amin[12 + r] = fminf(amin[12 + r], fmaf(-2.f, A3[r], QV));         \
        }                                                                      \
    }

    // combined epilogue: test (pre-update min) -> collect -> update min
#define EPIC(A0, A1, A2, A3, QV, CB)                                           \
    {                                                                          \
        _Pragma("unroll")                                                      \
        for (int vt = 0; vt < 4; ++vt) {                                       \
            const f32x4 aa = (vt == 0) ? A0 : (vt == 1) ? A1 : (vt == 2) ? A2 : A3; \
            _Pragma("unroll")                                                  \
            for (int r = 0; r < 4; ++r) {                                      \
                const int s = vt * 4 + r;                                      \
                float sc = fmaf(-2.f, aa[r], QV);                              \
                if (sc <= amin[s] + DELTA) {                                   \
                    const int vec = w * 64 + vt * 16 + ((lane >> 4) << 2) + r; \
                    int pos = atomicAdd(&ccnt[vec], 1);                        \
                    if (pos < CAP) cand[vec][pos] = (unsigned short)((CB) + col); \
                }                                                              \
                if (sc < amin[s]) amin[s] = sc;                                \
            }                                                                  \
        }                                                                      \
    }

#define SYNC_AMIN                                                              \
    {                                                                          \
        _Pragma("unroll")                                                      \
        for (int s = 0; s < 16; ++s) {                                         \
            float v = amin[s];                                                 \
            v = fminf(v, __shfl_xor(v, 1));                                    \
            v = fminf(v, __shfl_xor(v, 2));                                    \
            v = fminf(v, __shfl_xor(v, 4));                                    \
            v = fminf(v, __shfl_xor(v, 8));                                    \
            amin[s] = v;                                                       \
        }                                                                      \
    }

    // ---- depth-4 named prefetch slots ----
    short8v s0a, s0b, s1a, s1b, s2a, s2b, s3a, s3b;
    float   q0, q1, q2, q3;
    f32x4   xA0, xA1, xA2, xA3, yA0, yA1, yA2, yA3;
    LOADB2(0, s0a, s0b, q0);
    LOADB2(1, s1a, s1b, q1);
    LOADB2(2, s2a, s2b, q2);
    LOADB2(3, s3a, s3b, q3);

    // ================= warm-up: chunks 0..7, min-only ======================
#pragma unroll 1
    for (int g = 0; g < 2; ++g) {
        {   // chunks 4g, 4g+1
            short8v c0 = s0a, c1 = s0b; float qa = q0;
            short8v d0 = s1a, d1 = s1b; float qb = q1;
            LOADB2((4 * g + 4) & 127, s0a, s0b, q0);
            LOADB2((4 * g + 5) & 127, s1a, s1b, q1);
            MFMA4(c0, c1, xA0, xA1, xA2, xA3);
            MFMA4(d0, d1, yA0, yA1, yA2, yA3);
            EPI1(xA0, xA1, xA2, xA3, qa);
            EPI1(yA0, yA1, yA2, yA3, qb);
        }
        {   // chunks 4g+2, 4g+3
            short8v c0 = s2a, c1 = s2b; float qa = q2;
            short8v d0 = s3a, d1 = s3b; float qb = q3;
            LOADB2((4 * g + 6) & 127, s2a, s2b, q2);
            LOADB2((4 * g + 7) & 127, s3a, s3b, q3);
            MFMA4(c0, c1, xA0, xA1, xA2, xA3);
            MFMA4(d0, d1, yA0, yA1, yA2, yA3);
            EPI1(xA0, xA1, xA2, xA3, qa);
            EPI1(yA0, yA1, yA2, yA3, qb);
        }
    }
    SYNC_AMIN;   // per-vector min over first 128 codes: tight threshold

    // ========== single collecting scan: chunks 8..135 mod 128 ==============
    // slots currently hold chunks 8..11; prefetch (4g+12+i)&127.
#pragma unroll 1
    for (int g = 0; g < 32; ++g) {
        {   // pair 1
            const int cbA = ((8 + 4 * g + 0) & 127) << 4;
            const int cbB = ((8 + 4 * g + 1) & 127) << 4;
            short8v c0 = s0a, c1 = s0b; float qa = q0;
            short8v d0 = s1a, d1 = s1b; float qb = q1;
            LOADB2((4 * g + 12) & 127, s0a, s0b, q0);
            LOADB2((4 * g + 13) & 127, s1a, s1b, q1);
            MFMA4(c0, c1, xA0, xA1, xA2, xA3);
            MFMA4(d0, d1, yA0, yA1, yA2, yA3);
            EPIC(xA0, xA1, xA2, xA3, qa, cbA);
            EPIC(yA0, yA1, yA2, yA3, qb, cbB);
        }
        {   // pair 2
            const int cbA = ((8 + 4 * g + 2) & 127) << 4;
            const int cbB = ((8 + 4 * g + 3) & 127) << 4;
            short8v c0 = s2a, c1 = s2b; float qa = q2;
            short8v d0 = s3a, d1 = s3b; float qb = q3;
            LOADB2((4 * g + 14) & 127, s2a, s2b, q2);
            LOADB2((4 * g + 15) & 127, s3a, s3b, q3);
            MFMA4(c0, c1, xA0, xA1, xA2, xA3);
            MFMA4(d0, d1, yA0, yA1, yA2, yA3);
            EPIC(xA0, xA1, xA2, xA3, qa, cbA);
            EPIC(yA0, yA1, yA2, yA3, qb, cbB);
        }
        if ((g & 7) == 7) SYNC_AMIN;   // re-tighten every 32 chunks
    }
    __syncthreads();

    // ================= exact f32 rescore: thread tid <-> vec tid ============
    {
        const float4* xr = (const float4*)(x + (size_t)(n0 + tid) * HD + (size_t)h * D);
        const int nc = ccnt[tid];
        float bb = FLT_MAX;
        int   bi = 0x7fffffff;
        if (nc <= CAP) {
            for (int i = 0; i < nc; ++i) {
                const int code = cand[tid][i];
                const float4* er = (const float4*)(keh + (size_t)code * D);
                float s = 0.f;
#pragma unroll 4
                for (int kq = 0; kq < 16; ++kq) {
                    float4 a4 = xr[kq]; float4 e4 = er[kq];
                    s = fmaf(a4.x, e4.x, s); s = fmaf(a4.y, e4.y, s);
                    s = fmaf(a4.z, e4.z, s); s = fmaf(a4.w, e4.w, s);
                }
                float sc = fmaf(-2.f, s, esqh[code]);
                if (sc < bb || (sc == bb && code < bi)) { bb = sc; bi = code; }
            }
        } else {
            // deterministic fallback: full exact scan, ascending => first-min
            for (int code = 0; code < C; ++code) {
                const float4* er = (const float4*)(keh + (size_t)code * D);
                float s = 0.f;
#pragma unroll 4
                for (int kq = 0; kq < 16; ++kq) {
                    float4 a4 = xr[kq]; float4 e4 = er[kq];
                    s = fmaf(a4.x, e4.x, s); s = fmaf(a4.y, e4.y, s);
                    s = fmaf(a4.z, e4.z, s); s = fmaf(a4.w, e4.w, s);
                }
                float sc = fmaf(-2.f, s, esqh[code]);
                if (sc < bb) { bb = sc; bi = code; }
            }
        }
        sidx[tid] = bi;
        outi[(size_t)(n0 + tid) * H + h] = (float)bi;          // [b,t,h]
        indw[((size_t)h << 14) + n0 + tid] = (unsigned short)bi;
        atomicAdd(&counts[(h << 11) + bi], 1u);                // fused histogram
    }
    __syncthreads();

    // ---- gather quantized vectors (no atomics) ----
#pragma unroll
    for (int ii = 0; ii < 2; ++ii) {
        const int v  = ii * 128 + (tid >> 1);
        const int db = (tid & 1) * 32;
        const int ci = sidx[v];
        const float* ev = keh + (size_t)ci * D + db;
        float* qo = outq + (size_t)(n0 + v) * HD + (size_t)h * D + db;
#pragma unroll
        for (int i = 0; i < 8; ++i)
            ((float4*)qo)[i] = ((const float4*)ev)[i];
    }
}

// ---------------------------------------------------------------------------
// Kernel 3: per-head exclusive prefix scan of counts -> off, cur
// ---------------------------------------------------------------------------
__global__ __launch_bounds__(256) void vq_scan_kernel(const unsigned int* __restrict__ counts,
                                                      unsigned int* __restrict__ off,
                                                      unsigned int* __restrict__ cur) {
    __shared__ unsigned int sa[C], sb[C];
    const int h   = blockIdx.x;
    const int tid = threadIdx.x;
#pragma unroll
    for (int j = 0; j < 8; ++j) sa[j * 256 + tid] = counts[(h << 11) + j * 256 + tid];
    __syncthreads();
    unsigned int* src = sa;
    unsigned int* dst = sb;
    for (int s = 1; s < C; s <<= 1) {
#pragma unroll
        for (int j = 0; j < 8; ++j) {
            const int c = j * 256 + tid;
            unsigned int v = src[c];
            if (c >= s) v += src[c - s];
            dst[c] = v;
        }
        __syncthreads();
        unsigned int* t = src; src = dst; dst = t;
    }
#pragma unroll
    for (int j = 0; j < 8; ++j) {
        const int c = j * 256 + tid;
        const unsigned int e = c ? src[c - 1] : 0u;
        off[(h << 11) + c] = e;
        cur[(h << 11) + c] = e;
    }
}

// ---------------------------------------------------------------------------
// Kernel 4: scatter vec-ids into per-code lists (131K cursor atomics)
// ---------------------------------------------------------------------------
__global__ __launch_bounds__(256) void vq_scatter_kernel(const unsigned short* __restrict__ ind,
                                                         unsigned int* __restrict__ cur,
                                                         unsigned int* __restrict__ perm) {
    const int g = blockIdx.x * 256 + threadIdx.x;   // 131072
    const int h = g >> 14;
    const int n = g & 16383;
    const int c = ind[g];
    const unsigned int pos = atomicAdd(&cur[(h << 11) + c], 1u);
    perm[((size_t)h << 14) + pos] = (unsigned int)n;
}

// ---------------------------------------------------------------------------
// Kernel 5: segmented reduce + fused EMA lerp (R16 structure).
//   One block per (head,code); 4 waves stride entries; 4 f64 accs per wave;
//   fixed combine order => deterministic.
// ---------------------------------------------------------------------------
__global__ __launch_bounds__(256) void vq_reduce_kernel(const float* __restrict__ x,
                                                        const float* __restrict__ ke,
                                                        const unsigned int* __restrict__ perm,
                                                        const unsigned int* __restrict__ counts,
                                                        const unsigned int* __restrict__ off,
                                                        const int* __restrict__ ko,
                                                        float* __restrict__ outk) {
    __shared__ double sred[3][64];
    const int tid  = threadIdx.x;
    const int lane = tid & 63;
    const int w    = tid >> 6;
    const int pair = blockIdx.x;            // h*2048 + c
    const int h    = pair >> 11;

    const unsigned int cnt = counts[pair];
    const unsigned int o   = off[pair];
    const unsigned int* pl = perm + ((size_t)h << 14) + o;
    const float* xh = x + (size_t)h * D;    // + vid*HD + lane

    double a0 = 0.0, a1 = 0.0, a2 = 0.0, a3 = 0.0;
    unsigned int i = (unsigned int)w;
    for (; i + 12 < cnt; i += 16) {
        const unsigned int v0 = pl[i], v1 = pl[i + 4], v2 = pl[i + 8], v3 = pl[i + 12];
        a0 += (double)xh[(size_t)v0 * HD + lane];
        a1 += (double)xh[(size_t)v1 * HD + lane];
        a2 += (double)xh[(size_t)v2 * HD + lane];
        a3 += (double)xh[(size_t)v3 * HD + lane];
    }
    for (; i < cnt; i += 4)
        a0 += (double)xh[(size_t)pl[i] * HD + lane];
    const double part = ((a0 + a1) + a2) + a3;

    if (w) sred[w - 1][lane] = part;
    __syncthreads();
    if (w == 0) {
        const double acc = ((part + sred[0][lane]) + sred[1][lane]) + sred[2][lane];
        const float esum = (float)acc;
        const float kv   = ke[(size_t)pair * D + lane];
        const float ov   = ko[0] ? (kv + DECAYF * (esum - kv)) : kv;
        outk[(size_t)pair * D + lane] = ov;
    }
}

extern "C" void kernel_launch(void* const* d_in, const int* in_sizes, int n_in,
                              void* d_out, int out_size, void* d_ws, size_t ws_size,
                              hipStream_t stream) {
    const float* x  = (const float*)d_in[0];
    const float* ke = (const float*)d_in[1];
    const int*   ko = (const int*)d_in[2];

    float* out  = (float*)d_out;
    float* outq = out;                                   // 8,388,608 floats
    float* outi = out + (size_t)H * NPH * D;             // +131,072 floats
    float* outk = outi + (size_t)NPH * H;                // +1,048,576 floats

    // workspace layout
    float*          esq    = (float*)d_ws;                              // 16,384 f32
    unsigned short* keb2   = (unsigned short*)(esq + H * C);            // 1M u16 (swizzled)
    unsigned short* indw   = keb2 + (size_t)H * C * D;                  // 131,072 u16
    unsigned int*   counts = (unsigned int*)(indw + (size_t)H * NPH);   // 16,384 u32
    unsigned int*   offv   = counts + H * C;                            // 16,384 u32
    unsigned int*   curv   = offv + H * C;                              // 16,384 u32
    unsigned int*   perm   = curv + H * C;                              // 131,072 u32

    vq_prep_kernel<<<(H * C) / 256, 256, 0, stream>>>(ke, keb2, esq, counts);
    vq_main_kernel<<<512, 256, 0, stream>>>(x, keb2, ke, esq, outq, outi, indw, counts);
    vq_scan_kernel<<<H, 256, 0, stream>>>(counts, offv, curv);
    vq_scatter_kernel<<<512, 256, 0, stream>>>(indw, curv, perm);
    vq_reduce_kernel<<<H * C, 256, 0, stream>>>(x, ke, perm, counts, offv, ko, outk);
}

// Round 22
// 208.769 us; speedup vs baseline: 1.3736x; 1.3736x over previous
//
#include <hip/hip_runtime.h>
#include <float.h>

// VectorQuantize: h=8 heads, c=2048 codes, d=64, b=8, t=2048 (n=16384 vec/head)
#define H   8
#define C   2048
#define D   64
#define NPH 16384     // vectors per head (b*t)
#define HD  512       // h*d
#define DECAYF 0.9f
#define DELTA 3.0f    // candidate margin >= 2x worst-case bf16 score error (~0.6)
#define CAP 64        // per-vector candidate slots
#define VB  256       // vectors per block (512 blocks)

typedef __attribute__((ext_vector_type(8))) short short8v;   // 8 bf16 (4 VGPR)
typedef __attribute__((ext_vector_type(4))) float f32x4;

__device__ inline unsigned short f32_to_bf16_rne(float f) {
    unsigned int x = __float_as_uint(f);
    return (unsigned short)((x + 0x7FFFu + ((x >> 16) & 1u)) >> 16);
}

// ---------------------------------------------------------------------------
// Kernel 0: fused prep. Thread = one codebook row r = (h, ch*16+c):
//   esq[r] = serial-fmaf sum of squares; keb2 = bf16 codebook PRE-SWIZZLED
//   into MFMA-fragment-linear order (R15 win); counts[r] = 0.
// ---------------------------------------------------------------------------
__global__ __launch_bounds__(256) void vq_prep_kernel(const float* __restrict__ ke,
                                                      unsigned short* __restrict__ keb2,
                                                      float* __restrict__ esq,
                                                      unsigned int* __restrict__ counts) {
    const int row = blockIdx.x * 256 + threadIdx.x;   // 0 .. H*C-1
    const int c   = row & 15;
    const int ch  = (row >> 4) & 127;
    const int h   = row >> 11;
    const float* e = ke + (size_t)row * D;
    unsigned short* kb = keb2 + ((size_t)h * C * D) + (size_t)ch * 1024;
#pragma unroll
    for (int kf = 0; kf < 2; ++kf)
#pragma unroll
        for (int g = 0; g < 4; ++g) {
            float4 v0 = ((const float4*)e)[kf * 8 + g * 2];
            float4 v1 = ((const float4*)e)[kf * 8 + g * 2 + 1];
            short8v o;
            o[0] = (short)f32_to_bf16_rne(v0.x); o[1] = (short)f32_to_bf16_rne(v0.y);
            o[2] = (short)f32_to_bf16_rne(v0.z); o[3] = (short)f32_to_bf16_rne(v0.w);
            o[4] = (short)f32_to_bf16_rne(v1.x); o[5] = (short)f32_to_bf16_rne(v1.y);
            o[6] = (short)f32_to_bf16_rne(v1.z); o[7] = (short)f32_to_bf16_rne(v1.w);
            *(short8v*)(kb + kf * 512 + (g * 16 + c) * 8) = o;
        }
    float s = 0.f;
#pragma unroll
    for (int d = 0; d < D; ++d) s = fmaf(e[d], e[d], s);
    esq[row] = s;
    counts[row] = 0u;
}

// ---------------------------------------------------------------------------
// Kernel 1: MFMA screening + exact rescore (R20 VERBATIM -- best, 153us main).
//   Two-pass screen (single-pass regressed twice: R14, R21 -- always-collect
//   epilogue poisons scheduling). Paired-chunk MFMA batching (R20 +6%),
//   swizzled-B coalesced loads (R15), depth-4 named prefetch, CAP=64,
//   per-vector candidates, fused histogram, exact f32 rescore.
// ---------------------------------------------------------------------------
__global__ __launch_bounds__(256, 2)
void vq_main_kernel(const float* __restrict__ x,
                    const unsigned short* __restrict__ keb2,
                    const float* __restrict__ ke,
                    const float* __restrict__ esq,
                    float* __restrict__ outq,
                    float* __restrict__ outi,
                    unsigned short* __restrict__ indw,
                    unsigned int* __restrict__ counts) {
    __shared__ int            ccnt[VB];
    __shared__ unsigned short cand[VB][CAP];
    __shared__ int            sidx[VB];

    const int tid  = threadIdx.x;
    const int lane = tid & 63;
    const int w    = __builtin_amdgcn_readfirstlane(tid >> 6);
    const int h    = blockIdx.x & 7;
    const int n0   = (blockIdx.x >> 3) * VB;

    const unsigned short* keb2h = keb2 + (size_t)h * C * D;
    const float* keh  = ke  + (size_t)h * C * D;
    const float* esqh = esq + (size_t)h * C;

    ccnt[tid] = 0;
    __syncthreads();

    const int col = lane & 15;        // code col within 16-tile
    const int kg  = (lane >> 4) * 8;  // this lane's k-group base

    // ---- A-frags: lane's 4 vec-rows x 64 k, bf16, persistent ----
    short8v afr[4][2];
#pragma unroll
    for (int vt = 0; vt < 4; ++vt) {
        const float* xp = x + (size_t)(n0 + w * 64 + vt * 16 + col) * HD
                            + (size_t)h * D + kg;
#pragma unroll
        for (int kf = 0; kf < 2; ++kf) {
            float4 u0 = *(const float4*)(xp + kf * 32);
            float4 u1 = *(const float4*)(xp + kf * 32 + 4);
            short8v a;
            a[0] = (short)f32_to_bf16_rne(u0.x); a[1] = (short)f32_to_bf16_rne(u0.y);
            a[2] = (short)f32_to_bf16_rne(u0.z); a[3] = (short)f32_to_bf16_rne(u0.w);
            a[4] = (short)f32_to_bf16_rne(u1.x); a[5] = (short)f32_to_bf16_rne(u1.y);
            a[6] = (short)f32_to_bf16_rne(u1.z); a[7] = (short)f32_to_bf16_rne(u1.w);
            afr[vt][kf] = a;
        }
    }

    float amin[16];
#pragma unroll
    for (int s = 0; s < 16; ++s) amin[s] = FLT_MAX;

    // coalesced fragment load: B0 = kb[lane], B1 = kb[64+lane]
#define LOADB2(CH, B0, B1, EQ)                                                 \
    {                                                                          \
        const short8v* kb = (const short8v*)(keb2h + (size_t)(CH) * 1024);     \
        B0 = kb[lane];                                                         \
        B1 = kb[64 + lane];                                                    \
        EQ = esqh[((CH) << 4) + col];                                          \
    }

    // MFMA one chunk into 4 named accs (vt = 0..3)
#define MFMA4(C0V, C1V, A0, A1, A2, A3)                                        \
    {                                                                          \
        A0 = (f32x4){0.f, 0.f, 0.f, 0.f};                                      \
        A1 = (f32x4){0.f, 0.f, 0.f, 0.f};                                      \
        A2 = (f32x4){0.f, 0.f, 0.f, 0.f};                                      \
        A3 = (f32x4){0.f, 0.f, 0.f, 0.f};                                      \
        A0 = __builtin_amdgcn_mfma_f32_16x16x32_bf16(afr[0][0], C0V, A0, 0, 0, 0); \
        A1 = __builtin_amdgcn_mfma_f32_16x16x32_bf16(afr[1][0], C0V, A1, 0, 0, 0); \
        A2 = __builtin_amdgcn_mfma_f32_16x16x32_bf16(afr[2][0], C0V, A2, 0, 0, 0); \
        A3 = __builtin_amdgcn_mfma_f32_16x16x32_bf16(afr[3][0], C0V, A3, 0, 0, 0); \
        A0 = __builtin_amdgcn_mfma_f32_16x16x32_bf16(afr[0][1], C1V, A0, 0, 0, 0); \
        A1 = __builtin_amdgcn_mfma_f32_16x16x32_bf16(afr[1][1], C1V, A1, 0, 0, 0); \
        A2 = __builtin_amdgcn_mfma_f32_16x16x32_bf16(afr[2][1], C1V, A2, 0, 0, 0); \
        A3 = __builtin_amdgcn_mfma_f32_16x16x32_bf16(afr[3][1], C1V, A3, 0, 0, 0); \
    }

    // running-min epilogue for one chunk (pass 1)
#define EPI1(A0, A1, A2, A3, QV)                                               \
    {                                                                          \
        _Pragma("unroll")                                                      \
        for (int r = 0; r < 4; ++r) {                                          \
            amin[0 + r]  = fminf(amin[0 + r],  fmaf(-2.f, A0[r], QV));         \
            amin[4 + r]  = fminf(amin[4 + r],  fmaf(-2.f, A1[r], QV));         \
            amin[8 + r]  = fminf(amin[8 + r],  fmaf(-2.f, A2[r], QV));         \
            amin[12 + r] = fminf(amin[12 + r], fmaf(-2.f, A3[r], QV));         \
        }                                                                      \
    }

    // candidate-collect epilogue for one chunk (pass 2)
#define EPI2(A0, A1, A2, A3, QV, CB)                                           \
    {                                                                          \
        _Pragma("unroll")                                                      \
        for (int vt = 0; vt < 4; ++vt) {                                       \
            const f32x4 aa = (vt == 0) ? A0 : (vt == 1) ? A1 : (vt == 2) ? A2 : A3; \
            _Pragma("unroll")                                                  \
            for (int r = 0; r < 4; ++r) {                                      \
                float sc = fmaf(-2.f, aa[r], QV);                              \
                if (sc <= amin[vt * 4 + r] + DELTA) {                          \
                    const int vec = w * 64 + vt * 16 + ((lane >> 4) << 2) + r; \
                    int pos = atomicAdd(&ccnt[vec], 1);                        \
                    if (pos < CAP) cand[vec][pos] = (unsigned short)((CB) + col); \
                }                                                              \
            }                                                                  \
        }                                                                      \
    }

    // ================= pass 1: per-vector approx min ========================
    {
        short8v s0a, s0b, s1a, s1b, s2a, s2b, s3a, s3b;
        float   q0, q1, q2, q3;
        LOADB2(0, s0a, s0b, q0);
        LOADB2(1, s1a, s1b, q1);
        LOADB2(2, s2a, s2b, q2);
        LOADB2(3, s3a, s3b, q3);
        f32x4 xA0, xA1, xA2, xA3, yA0, yA1, yA2, yA3;
#pragma unroll 1
        for (int g = 0; g < 32; ++g) {
            {   // pair 1: chunks 4g, 4g+1
                short8v c0 = s0a, c1 = s0b; float qa = q0;
                short8v d0 = s1a, d1 = s1b; float qb = q1;
                LOADB2((4 * g + 4) & 127, s0a, s0b, q0);
                LOADB2((4 * g + 5) & 127, s1a, s1b, q1);
                MFMA4(c0, c1, xA0, xA1, xA2, xA3);
                MFMA4(d0, d1, yA0, yA1, yA2, yA3);
                EPI1(xA0, xA1, xA2, xA3, qa);
                EPI1(yA0, yA1, yA2, yA3, qb);
            }
            {   // pair 2: chunks 4g+2, 4g+3
                short8v c0 = s2a, c1 = s2b; float qa = q2;
                short8v d0 = s3a, d1 = s3b; float qb = q3;
                LOADB2((4 * g + 6) & 127, s2a, s2b, q2);
                LOADB2((4 * g + 7) & 127, s3a, s3b, q3);
                MFMA4(c0, c1, xA0, xA1, xA2, xA3);
                MFMA4(d0, d1, yA0, yA1, yA2, yA3);
                EPI1(xA0, xA1, xA2, xA3, qa);
                EPI1(yA0, yA1, yA2, yA3, qb);
            }
        }
    }

    // cross-lane min over the 16 lanes sharing (lane>>4)
#pragma unroll
    for (int s = 0; s < 16; ++s) {
        float v = amin[s];
        v = fminf(v, __shfl_xor(v, 1));
        v = fminf(v, __shfl_xor(v, 2));
        v = fminf(v, __shfl_xor(v, 4));
        v = fminf(v, __shfl_xor(v, 8));
        amin[s] = v;
    }

    // ================= pass 2: collect candidates per VECTOR ================
    {
        short8v s0a, s0b, s1a, s1b, s2a, s2b, s3a, s3b;
        float   q0, q1, q2, q3;
        LOADB2(0, s0a, s0b, q0);
        LOADB2(1, s1a, s1b, q1);
        LOADB2(2, s2a, s2b, q2);
        LOADB2(3, s3a, s3b, q3);
        f32x4 xA0, xA1, xA2, xA3, yA0, yA1, yA2, yA3;
#pragma unroll 1
        for (int g = 0; g < 32; ++g) {
            {   // pair 1: chunks 4g, 4g+1
                short8v c0 = s0a, c1 = s0b; float qa = q0;
                short8v d0 = s1a, d1 = s1b; float qb = q1;
                LOADB2((4 * g + 4) & 127, s0a, s0b, q0);
                LOADB2((4 * g + 5) & 127, s1a, s1b, q1);
                MFMA4(c0, c1, xA0, xA1, xA2, xA3);
                MFMA4(d0, d1, yA0, yA1, yA2, yA3);
                EPI2(xA0, xA1, xA2, xA3, qa, (4 * g + 0) << 4);
                EPI2(yA0, yA1, yA2, yA3, qb, (4 * g + 1) << 4);
            }
            {   // pair 2: chunks 4g+2, 4g+3
                short8v c0 = s2a, c1 = s2b; float qa = q2;
                short8v d0 = s3a, d1 = s3b; float qb = q3;
                LOADB2((4 * g + 6) & 127, s2a, s2b, q2);
                LOADB2((4 * g + 7) & 127, s3a, s3b, q3);
                MFMA4(c0, c1, xA0, xA1, xA2, xA3);
                MFMA4(d0, d1, yA0, yA1, yA2, yA3);
                EPI2(xA0, xA1, xA2, xA3, qa, (4 * g + 2) << 4);
                EPI2(yA0, yA1, yA2, yA3, qb, (4 * g + 3) << 4);
            }
        }
    }
    __syncthreads();

    // ================= exact f32 rescore: thread tid <-> vec tid ============
    {
        const float4* xr = (const float4*)(x + (size_t)(n0 + tid) * HD + (size_t)h * D);
        const int nc = ccnt[tid];
        float bb = FLT_MAX;
        int   bi = 0x7fffffff;
        if (nc <= CAP) {
            for (int i = 0; i < nc; ++i) {
                const int code = cand[tid][i];
                const float4* er = (const float4*)(keh + (size_t)code * D);
                float s = 0.f;
#pragma unroll 4
                for (int kq = 0; kq < 16; ++kq) {
                    float4 a4 = xr[kq]; float4 e4 = er[kq];
                    s = fmaf(a4.x, e4.x, s); s = fmaf(a4.y, e4.y, s);
                    s = fmaf(a4.z, e4.z, s); s = fmaf(a4.w, e4.w, s);
                }
                float sc = fmaf(-2.f, s, esqh[code]);
                if (sc < bb || (sc == bb && code < bi)) { bb = sc; bi = code; }
            }
        } else {
            // deterministic fallback: full exact scan, ascending => first-min
            for (int code = 0; code < C; ++code) {
                const float4* er = (const float4*)(keh + (size_t)code * D);
                float s = 0.f;
#pragma unroll 4
                for (int kq = 0; kq < 16; ++kq) {
                    float4 a4 = xr[kq]; float4 e4 = er[kq];
                    s = fmaf(a4.x, e4.x, s); s = fmaf(a4.y, e4.y, s);
                    s = fmaf(a4.z, e4.z, s); s = fmaf(a4.w, e4.w, s);
                }
                float sc = fmaf(-2.f, s, esqh[code]);
                if (sc < bb) { bb = sc; bi = code; }
            }
        }
        sidx[tid] = bi;
        outi[(size_t)(n0 + tid) * H + h] = (float)bi;          // [b,t,h]
        indw[((size_t)h << 14) + n0 + tid] = (unsigned short)bi;
        atomicAdd(&counts[(h << 11) + bi], 1u);                // fused histogram
    }
    __syncthreads();

    // ---- gather quantized vectors (no atomics) ----
#pragma unroll
    for (int ii = 0; ii < 2; ++ii) {
        const int v  = ii * 128 + (tid >> 1);
        const int db = (tid & 1) * 32;
        const int ci = sidx[v];
        const float* ev = keh + (size_t)ci * D + db;
        float* qo = outq + (size_t)(n0 + v) * HD + (size_t)h * D + db;
#pragma unroll
        for (int i = 0; i < 8; ++i)
            ((float4*)qo)[i] = ((const float4*)ev)[i];
    }
}

// ---------------------------------------------------------------------------
// Kernel 3: FUSED per-head scan + scatter. Block h: exclusive prefix scan of
//   counts[h] in LDS -> off (global); then scatter all 16384 of head h's
//   vec-ids into per-code lists via LDS cursors. Within-code order differs
//   from the old global-atomic version, but the reduce is f64 + fixed
//   combine order => result identical after f32 rounding (R16 argument).
//   Saves one kernel launch and the curv buffer.
// ---------------------------------------------------------------------------
__global__ __launch_bounds__(256) void vq_scan_scatter_kernel(
        const unsigned int* __restrict__ counts,
        const unsigned short* __restrict__ ind,
        unsigned int* __restrict__ off,
        unsigned short* __restrict__ perm) {
    __shared__ unsigned int sa[C], sb[C];
    const int h   = blockIdx.x;
    const int tid = threadIdx.x;
#pragma unroll
    for (int j = 0; j < 8; ++j) sa[j * 256 + tid] = counts[(h << 11) + j * 256 + tid];
    __syncthreads();
    unsigned int* src = sa;
    unsigned int* dst = sb;
    for (int s = 1; s < C; s <<= 1) {
#pragma unroll
        for (int j = 0; j < 8; ++j) {
            const int c = j * 256 + tid;
            unsigned int v = src[c];
            if (c >= s) v += src[c - s];
            dst[c] = v;
        }
        __syncthreads();
        unsigned int* t = src; src = dst; dst = t;
    }
    // src = inclusive scan; write exclusive offsets to global and LDS cursors
    unsigned int* cur = dst;    // reuse the other buffer as cursor array
#pragma unroll
    for (int j = 0; j < 8; ++j) {
        const int c = j * 256 + tid;
        const unsigned int e = c ? src[c - 1] : 0u;
        off[(h << 11) + c] = e;
        cur[c] = e;
    }
    __syncthreads();

    // scatter head h's 16384 entries; thread tid handles i = tid + 256*k
    const unsigned short* ih = ind + ((size_t)h << 14);
    unsigned short* ph = perm + ((size_t)h << 14);
#pragma unroll 1
    for (int k = 0; k < 64; ++k) {
        const int i = k * 256 + tid;
        const int c = ih[i];
        const unsigned int pos = atomicAdd(&cur[c], 1u);
        ph[pos] = (unsigned short)i;
    }
}

// ---------------------------------------------------------------------------
// Kernel 5: segmented reduce + fused EMA lerp (R16 structure).
//   One block per (head,code); 4 waves stride entries; 4 f64 accs per wave;
//   fixed combine order => deterministic.
// ---------------------------------------------------------------------------
__global__ __launch_bounds__(256) void vq_reduce_kernel(const float* __restrict__ x,
                                                        const float* __restrict__ ke,
                                                        const unsigned short* __restrict__ perm,
                                                        const unsigned int* __restrict__ counts,
                                                        const unsigned int* __restrict__ off,
                                                        const int* __restrict__ ko,
                                                        float* __restrict__ outk) {
    __shared__ double sred[3][64];
    const int tid  = threadIdx.x;
    const int lane = tid & 63;
    const int w    = tid >> 6;
    const int pair = blockIdx.x;            // h*2048 + c
    const int h    = pair >> 11;

    const unsigned int cnt = counts[pair];
    const unsigned int o   = off[pair];
    const unsigned short* pl = perm + ((size_t)h << 14) + o;
    const float* xh = x + (size_t)h * D;    // + vid*HD + lane

    double a0 = 0.0, a1 = 0.0, a2 = 0.0, a3 = 0.0;
    unsigned int i = (unsigned int)w;
    for (; i + 12 < cnt; i += 16) {
        const unsigned int v0 = pl[i], v1 = pl[i + 4], v2 = pl[i + 8], v3 = pl[i + 12];
        a0 += (double)xh[(size_t)v0 * HD + lane];
        a1 += (double)xh[(size_t)v1 * HD + lane];
        a2 += (double)xh[(size_t)v2 * HD + lane];
        a3 += (double)xh[(size_t)v3 * HD + lane];
    }
    for (; i < cnt; i += 4)
        a0 += (double)xh[(size_t)pl[i] * HD + lane];
    const double part = ((a0 + a1) + a2) + a3;

    if (w) sred[w - 1][lane] = part;
    __syncthreads();
    if (w == 0) {
        const double acc = ((part + sred[0][lane]) + sred[1][lane]) + sred[2][lane];
        const float esum = (float)acc;
        const float kv   = ke[(size_t)pair * D + lane];
        const float ov   = ko[0] ? (kv + DECAYF * (esum - kv)) : kv;
        outk[(size_t)pair * D + lane] = ov;
    }
}

extern "C" void kernel_launch(void* const* d_in, const int* in_sizes, int n_in,
                              void* d_out, int out_size, void* d_ws, size_t ws_size,
                              hipStream_t stream) {
    const float* x  = (const float*)d_in[0];
    const float* ke = (const float*)d_in[1];
    const int*   ko = (const int*)d_in[2];

    float* out  = (float*)d_out;
    float* outq = out;                                   // 8,388,608 floats
    float* outi = out + (size_t)H * NPH * D;             // +131,072 floats
    float* outk = outi + (size_t)NPH * H;                // +1,048,576 floats

    // workspace layout
    float*          esq    = (float*)d_ws;                              // 16,384 f32
    unsigned short* keb2   = (unsigned short*)(esq + H * C);            // 1M u16 (swizzled)
    unsigned short* indw   = keb2 + (size_t)H * C * D;                  // 131,072 u16
    unsigned int*   counts = (unsigned int*)(indw + (size_t)H * NPH);   // 16,384 u32
    unsigned int*   offv   = counts + H * C;                            // 16,384 u32
    unsigned short* perm   = (unsigned short*)(offv + H * C);           // 131,072 u16

    vq_prep_kernel<<<(H * C) / 256, 256, 0, stream>>>(ke, keb2, esq, counts);
    vq_main_kernel<<<512, 256, 0, stream>>>(x, keb2, ke, esq, outq, outi, indw, counts);
    vq_scan_scatter_kernel<<<H, 256, 0, stream>>>(counts, indw, offv, perm);
    vq_reduce_kernel<<<H * C, 256, 0, stream>>>(x, ke, perm, counts, offv, ko, outk);
}

// Round 23
// 194.142 us; speedup vs baseline: 1.4771x; 1.0753x over previous
//
#include <hip/hip_runtime.h>
#include <float.h>

// VectorQuantize: h=8 heads, c=2048 codes, d=64, b=8, t=2048 (n=16384 vec/head)
// FINAL (R23 = R20 verbatim, session best 194.8us):
//   prep (swizzle+esq+zero) -> MFMA screen + exact rescore -> scan -> scatter
//   -> segmented f64 reduce + EMA lerp.
// Session wins baked in: no mass atomics (R12, -500us), fragment-linear
// swizzled codebook (R15, -160us), parallel segmented reduce (R16, -140us),
// paired-chunk MFMA batching + fused histogram/memset (R20, -14us).
// R22's scan+scatter fusion regressed (8-block serial scatter) -- reverted.
#define H   8
#define C   2048
#define D   64
#define NPH 16384     // vectors per head (b*t)
#define HD  512       // h*d
#define DECAYF 0.9f
#define DELTA 3.0f    // candidate margin >= 2x worst-case bf16 score error (~0.6)
#define CAP 64        // per-vector candidate slots
#define VB  256       // vectors per block (512 blocks)

typedef __attribute__((ext_vector_type(8))) short short8v;   // 8 bf16 (4 VGPR)
typedef __attribute__((ext_vector_type(4))) float f32x4;

__device__ inline unsigned short f32_to_bf16_rne(float f) {
    unsigned int x = __float_as_uint(f);
    return (unsigned short)((x + 0x7FFFu + ((x >> 16) & 1u)) >> 16);
}

// ---------------------------------------------------------------------------
// Kernel 0: fused prep. Thread = one codebook row r = (h, ch*16+c):
//   esq[r] = serial-fmaf sum of squares; keb2 = bf16 codebook PRE-SWIZZLED
//   into MFMA-fragment-linear order (R15 win); counts[r] = 0.
// ---------------------------------------------------------------------------
__global__ __launch_bounds__(256) void vq_prep_kernel(const float* __restrict__ ke,
                                                      unsigned short* __restrict__ keb2,
                                                      float* __restrict__ esq,
                                                      unsigned int* __restrict__ counts) {
    const int row = blockIdx.x * 256 + threadIdx.x;   // 0 .. H*C-1
    const int c   = row & 15;
    const int ch  = (row >> 4) & 127;
    const int h   = row >> 11;
    const float* e = ke + (size_t)row * D;
    unsigned short* kb = keb2 + ((size_t)h * C * D) + (size_t)ch * 1024;
#pragma unroll
    for (int kf = 0; kf < 2; ++kf)
#pragma unroll
        for (int g = 0; g < 4; ++g) {
            float4 v0 = ((const float4*)e)[kf * 8 + g * 2];
            float4 v1 = ((const float4*)e)[kf * 8 + g * 2 + 1];
            short8v o;
            o[0] = (short)f32_to_bf16_rne(v0.x); o[1] = (short)f32_to_bf16_rne(v0.y);
            o[2] = (short)f32_to_bf16_rne(v0.z); o[3] = (short)f32_to_bf16_rne(v0.w);
            o[4] = (short)f32_to_bf16_rne(v1.x); o[5] = (short)f32_to_bf16_rne(v1.y);
            o[6] = (short)f32_to_bf16_rne(v1.z); o[7] = (short)f32_to_bf16_rne(v1.w);
            *(short8v*)(kb + kf * 512 + (g * 16 + c) * 8) = o;
        }
    float s = 0.f;
#pragma unroll
    for (int d = 0; d < D; ++d) s = fmaf(e[d], e[d], s);
    esq[row] = s;
    counts[row] = 0u;
}

// ---------------------------------------------------------------------------
// Kernel 1: MFMA screening + exact rescore (R20 verbatim -- best, 153us).
//   Two-pass screen (single-pass regressed twice: R14/R21 -- always-collect
//   epilogue poisons scheduling). Paired-chunk MFMA batching, swizzled-B
//   coalesced loads, depth-4 named prefetch, CAP=64, per-vector candidates,
//   fused histogram, exact f32 rescore (fmaf k-ascending, fmaf(-2,dot,esq),
//   lexicographic (score,idx) min => first-min-by-index).
// ---------------------------------------------------------------------------
__global__ __launch_bounds__(256, 2)
void vq_main_kernel(const float* __restrict__ x,
                    const unsigned short* __restrict__ keb2,
                    const float* __restrict__ ke,
                    const float* __restrict__ esq,
                    float* __restrict__ outq,
                    float* __restrict__ outi,
                    unsigned short* __restrict__ indw,
                    unsigned int* __restrict__ counts) {
    __shared__ int            ccnt[VB];
    __shared__ unsigned short cand[VB][CAP];
    __shared__ int            sidx[VB];

    const int tid  = threadIdx.x;
    const int lane = tid & 63;
    const int w    = __builtin_amdgcn_readfirstlane(tid >> 6);
    const int h    = blockIdx.x & 7;
    const int n0   = (blockIdx.x >> 3) * VB;

    const unsigned short* keb2h = keb2 + (size_t)h * C * D;
    const float* keh  = ke  + (size_t)h * C * D;
    const float* esqh = esq + (size_t)h * C;

    ccnt[tid] = 0;
    __syncthreads();

    const int col = lane & 15;        // code col within 16-tile
    const int kg  = (lane >> 4) * 8;  // this lane's k-group base

    // ---- A-frags: lane's 4 vec-rows x 64 k, bf16, persistent ----
    short8v afr[4][2];
#pragma unroll
    for (int vt = 0; vt < 4; ++vt) {
        const float* xp = x + (size_t)(n0 + w * 64 + vt * 16 + col) * HD
                            + (size_t)h * D + kg;
#pragma unroll
        for (int kf = 0; kf < 2; ++kf) {
            float4 u0 = *(const float4*)(xp + kf * 32);
            float4 u1 = *(const float4*)(xp + kf * 32 + 4);
            short8v a;
            a[0] = (short)f32_to_bf16_rne(u0.x); a[1] = (short)f32_to_bf16_rne(u0.y);
            a[2] = (short)f32_to_bf16_rne(u0.z); a[3] = (short)f32_to_bf16_rne(u0.w);
            a[4] = (short)f32_to_bf16_rne(u1.x); a[5] = (short)f32_to_bf16_rne(u1.y);
            a[6] = (short)f32_to_bf16_rne(u1.z); a[7] = (short)f32_to_bf16_rne(u1.w);
            afr[vt][kf] = a;
        }
    }

    float amin[16];
#pragma unroll
    for (int s = 0; s < 16; ++s) amin[s] = FLT_MAX;

    // coalesced fragment load: B0 = kb[lane], B1 = kb[64+lane]
#define LOADB2(CH, B0, B1, EQ)                                                 \
    {                                                                          \
        const short8v* kb = (const short8v*)(keb2h + (size_t)(CH) * 1024);     \
        B0 = kb[lane];                                                         \
        B1 = kb[64 + lane];                                                    \
        EQ = esqh[((CH) << 4) + col];                                          \
    }

    // MFMA one chunk into 4 named accs (vt = 0..3)
#define MFMA4(C0V, C1V, A0, A1, A2, A3)                                        \
    {                                                                          \
        A0 = (f32x4){0.f, 0.f, 0.f, 0.f};                                      \
        A1 = (f32x4){0.f, 0.f, 0.f, 0.f};                                      \
        A2 = (f32x4){0.f, 0.f, 0.f, 0.f};                                      \
        A3 = (f32x4){0.f, 0.f, 0.f, 0.f};                                      \
        A0 = __builtin_amdgcn_mfma_f32_16x16x32_bf16(afr[0][0], C0V, A0, 0, 0, 0); \
        A1 = __builtin_amdgcn_mfma_f32_16x16x32_bf16(afr[1][0], C0V, A1, 0, 0, 0); \
        A2 = __builtin_amdgcn_mfma_f32_16x16x32_bf16(afr[2][0], C0V, A2, 0, 0, 0); \
        A3 = __builtin_amdgcn_mfma_f32_16x16x32_bf16(afr[3][0], C0V, A3, 0, 0, 0); \
        A0 = __builtin_amdgcn_mfma_f32_16x16x32_bf16(afr[0][1], C1V, A0, 0, 0, 0); \
        A1 = __builtin_amdgcn_mfma_f32_16x16x32_bf16(afr[1][1], C1V, A1, 0, 0, 0); \
        A2 = __builtin_amdgcn_mfma_f32_16x16x32_bf16(afr[2][1], C1V, A2, 0, 0, 0); \
        A3 = __builtin_amdgcn_mfma_f32_16x16x32_bf16(afr[3][1], C1V, A3, 0, 0, 0); \
    }

    // running-min epilogue for one chunk (pass 1)
#define EPI1(A0, A1, A2, A3, QV)                                               \
    {                                                                          \
        _Pragma("unroll")                                                      \
        for (int r = 0; r < 4; ++r) {                                          \
            amin[0 + r]  = fminf(amin[0 + r],  fmaf(-2.f, A0[r], QV));         \
            amin[4 + r]  = fminf(amin[4 + r],  fmaf(-2.f, A1[r], QV));         \
            amin[8 + r]  = fminf(amin[8 + r],  fmaf(-2.f, A2[r], QV));         \
            amin[12 + r] = fminf(amin[12 + r], fmaf(-2.f, A3[r], QV));         \
        }                                                                      \
    }

    // candidate-collect epilogue for one chunk (pass 2)
#define EPI2(A0, A1, A2, A3, QV, CB)                                           \
    {                                                                          \
        _Pragma("unroll")                                                      \
        for (int vt = 0; vt < 4; ++vt) {                                       \
            const f32x4 aa = (vt == 0) ? A0 : (vt == 1) ? A1 : (vt == 2) ? A2 : A3; \
            _Pragma("unroll")                                                  \
            for (int r = 0; r < 4; ++r) {                                      \
                float sc = fmaf(-2.f, aa[r], QV);                              \
                if (sc <= amin[vt * 4 + r] + DELTA) {                          \
                    const int vec = w * 64 + vt * 16 + ((lane >> 4) << 2) + r; \
                    int pos = atomicAdd(&ccnt[vec], 1);                        \
                    if (pos < CAP) cand[vec][pos] = (unsigned short)((CB) + col); \
                }                                                              \
            }                                                                  \
        }                                                                      \
    }

    // ================= pass 1: per-vector approx min ========================
    {
        short8v s0a, s0b, s1a, s1b, s2a, s2b, s3a, s3b;
        float   q0, q1, q2, q3;
        LOADB2(0, s0a, s0b, q0);
        LOADB2(1, s1a, s1b, q1);
        LOADB2(2, s2a, s2b, q2);
        LOADB2(3, s3a, s3b, q3);
        f32x4 xA0, xA1, xA2, xA3, yA0, yA1, yA2, yA3;
#pragma unroll 1
        for (int g = 0; g < 32; ++g) {
            {   // pair 1: chunks 4g, 4g+1
                short8v c0 = s0a, c1 = s0b; float qa = q0;
                short8v d0 = s1a, d1 = s1b; float qb = q1;
                LOADB2((4 * g + 4) & 127, s0a, s0b, q0);
                LOADB2((4 * g + 5) & 127, s1a, s1b, q1);
                MFMA4(c0, c1, xA0, xA1, xA2, xA3);
                MFMA4(d0, d1, yA0, yA1, yA2, yA3);
                EPI1(xA0, xA1, xA2, xA3, qa);
                EPI1(yA0, yA1, yA2, yA3, qb);
            }
            {   // pair 2: chunks 4g+2, 4g+3
                short8v c0 = s2a, c1 = s2b; float qa = q2;
                short8v d0 = s3a, d1 = s3b; float qb = q3;
                LOADB2((4 * g + 6) & 127, s2a, s2b, q2);
                LOADB2((4 * g + 7) & 127, s3a, s3b, q3);
                MFMA4(c0, c1, xA0, xA1, xA2, xA3);
                MFMA4(d0, d1, yA0, yA1, yA2, yA3);
                EPI1(xA0, xA1, xA2, xA3, qa);
                EPI1(yA0, yA1, yA2, yA3, qb);
            }
        }
    }

    // cross-lane min over the 16 lanes sharing (lane>>4)
#pragma unroll
    for (int s = 0; s < 16; ++s) {
        float v = amin[s];
        v = fminf(v, __shfl_xor(v, 1));
        v = fminf(v, __shfl_xor(v, 2));
        v = fminf(v, __shfl_xor(v, 4));
        v = fminf(v, __shfl_xor(v, 8));
        amin[s] = v;
    }

    // ================= pass 2: collect candidates per VECTOR ================
    {
        short8v s0a, s0b, s1a, s1b, s2a, s2b, s3a, s3b;
        float   q0, q1, q2, q3;
        LOADB2(0, s0a, s0b, q0);
        LOADB2(1, s1a, s1b, q1);
        LOADB2(2, s2a, s2b, q2);
        LOADB2(3, s3a, s3b, q3);
        f32x4 xA0, xA1, xA2, xA3, yA0, yA1, yA2, yA3;
#pragma unroll 1
        for (int g = 0; g < 32; ++g) {
            {   // pair 1: chunks 4g, 4g+1
                short8v c0 = s0a, c1 = s0b; float qa = q0;
                short8v d0 = s1a, d1 = s1b; float qb = q1;
                LOADB2((4 * g + 4) & 127, s0a, s0b, q0);
                LOADB2((4 * g + 5) & 127, s1a, s1b, q1);
                MFMA4(c0, c1, xA0, xA1, xA2, xA3);
                MFMA4(d0, d1, yA0, yA1, yA2, yA3);
                EPI2(xA0, xA1, xA2, xA3, qa, (4 * g + 0) << 4);
                EPI2(yA0, yA1, yA2, yA3, qb, (4 * g + 1) << 4);
            }
            {   // pair 2: chunks 4g+2, 4g+3
                short8v c0 = s2a, c1 = s2b; float qa = q2;
                short8v d0 = s3a, d1 = s3b; float qb = q3;
                LOADB2((4 * g + 6) & 127, s2a, s2b, q2);
                LOADB2((4 * g + 7) & 127, s3a, s3b, q3);
                MFMA4(c0, c1, xA0, xA1, xA2, xA3);
                MFMA4(d0, d1, yA0, yA1, yA2, yA3);
                EPI2(xA0, xA1, xA2, xA3, qa, (4 * g + 2) << 4);
                EPI2(yA0, yA1, yA2, yA3, qb, (4 * g + 3) << 4);
            }
        }
    }
    __syncthreads();

    // ================= exact f32 rescore: thread tid <-> vec tid ============
    {
        const float4* xr = (const float4*)(x + (size_t)(n0 + tid) * HD + (size_t)h * D);
        const int nc = ccnt[tid];
        float bb = FLT_MAX;
        int   bi = 0x7fffffff;
        if (nc <= CAP) {
            for (int i = 0; i < nc; ++i) {
                const int code = cand[tid][i];
                const float4* er = (const float4*)(keh + (size_t)code * D);
                float s = 0.f;
#pragma unroll 4
                for (int kq = 0; kq < 16; ++kq) {
                    float4 a4 = xr[kq]; float4 e4 = er[kq];
                    s = fmaf(a4.x, e4.x, s); s = fmaf(a4.y, e4.y, s);
                    s = fmaf(a4.z, e4.z, s); s = fmaf(a4.w, e4.w, s);
                }
                float sc = fmaf(-2.f, s, esqh[code]);
                if (sc < bb || (sc == bb && code < bi)) { bb = sc; bi = code; }
            }
        } else {
            // deterministic fallback: full exact scan, ascending => first-min
            for (int code = 0; code < C; ++code) {
                const float4* er = (const float4*)(keh + (size_t)code * D);
                float s = 0.f;
#pragma unroll 4
                for (int kq = 0; kq < 16; ++kq) {
                    float4 a4 = xr[kq]; float4 e4 = er[kq];
                    s = fmaf(a4.x, e4.x, s); s = fmaf(a4.y, e4.y, s);
                    s = fmaf(a4.z, e4.z, s); s = fmaf(a4.w, e4.w, s);
                }
                float sc = fmaf(-2.f, s, esqh[code]);
                if (sc < bb) { bb = sc; bi = code; }
            }
        }
        sidx[tid] = bi;
        outi[(size_t)(n0 + tid) * H + h] = (float)bi;          // [b,t,h]
        indw[((size_t)h << 14) + n0 + tid] = (unsigned short)bi;
        atomicAdd(&counts[(h << 11) + bi], 1u);                // fused histogram
    }
    __syncthreads();

    // ---- gather quantized vectors (no atomics) ----
#pragma unroll
    for (int ii = 0; ii < 2; ++ii) {
        const int v  = ii * 128 + (tid >> 1);
        const int db = (tid & 1) * 32;
        const int ci = sidx[v];
        const float* ev = keh + (size_t)ci * D + db;
        float* qo = outq + (size_t)(n0 + v) * HD + (size_t)h * D + db;
#pragma unroll
        for (int i = 0; i < 8; ++i)
            ((float4*)qo)[i] = ((const float4*)ev)[i];
    }
}

// ---------------------------------------------------------------------------
// Kernel 3: per-head exclusive prefix scan of counts -> off, cur
// ---------------------------------------------------------------------------
__global__ __launch_bounds__(256) void vq_scan_kernel(const unsigned int* __restrict__ counts,
                                                      unsigned int* __restrict__ off,
                                                      unsigned int* __restrict__ cur) {
    __shared__ unsigned int sa[C], sb[C];
    const int h   = blockIdx.x;
    const int tid = threadIdx.x;
#pragma unroll
    for (int j = 0; j < 8; ++j) sa[j * 256 + tid] = counts[(h << 11) + j * 256 + tid];
    __syncthreads();
    unsigned int* src = sa;
    unsigned int* dst = sb;
    for (int s = 1; s < C; s <<= 1) {
#pragma unroll
        for (int j = 0; j < 8; ++j) {
            const int c = j * 256 + tid;
            unsigned int v = src[c];
            if (c >= s) v += src[c - s];
            dst[c] = v;
        }
        __syncthreads();
        unsigned int* t = src; src = dst; dst = t;
    }
#pragma unroll
    for (int j = 0; j < 8; ++j) {
        const int c = j * 256 + tid;
        const unsigned int e = c ? src[c - 1] : 0u;
        off[(h << 11) + c] = e;
        cur[(h << 11) + c] = e;
    }
}

// ---------------------------------------------------------------------------
// Kernel 4: scatter vec-ids into per-code lists (131K cursor atomics)
// ---------------------------------------------------------------------------
__global__ __launch_bounds__(256) void vq_scatter_kernel(const unsigned short* __restrict__ ind,
                                                         unsigned int* __restrict__ cur,
                                                         unsigned int* __restrict__ perm) {
    const int g = blockIdx.x * 256 + threadIdx.x;   // 131072
    const int h = g >> 14;
    const int n = g & 16383;
    const int c = ind[g];
    const unsigned int pos = atomicAdd(&cur[(h << 11) + c], 1u);
    perm[((size_t)h << 14) + pos] = (unsigned int)n;
}

// ---------------------------------------------------------------------------
// Kernel 5: segmented reduce + fused EMA lerp (R16 structure).
//   One block per (head,code); 4 waves stride entries; 4 f64 accs per wave;
//   fixed combine order => deterministic.
// ---------------------------------------------------------------------------
__global__ __launch_bounds__(256) void vq_reduce_kernel(const float* __restrict__ x,
                                                        const float* __restrict__ ke,
                                                        const unsigned int* __restrict__ perm,
                                                        const unsigned int* __restrict__ counts,
                                                        const unsigned int* __restrict__ off,
                                                        const int* __restrict__ ko,
                                                        float* __restrict__ outk) {
    __shared__ double sred[3][64];
    const int tid  = threadIdx.x;
    const int lane = tid & 63;
    const int w    = tid >> 6;
    const int pair = blockIdx.x;            // h*2048 + c
    const int h    = pair >> 11;

    const unsigned int cnt = counts[pair];
    const unsigned int o   = off[pair];
    const unsigned int* pl = perm + ((size_t)h << 14) + o;
    const float* xh = x + (size_t)h * D;    // + vid*HD + lane

    double a0 = 0.0, a1 = 0.0, a2 = 0.0, a3 = 0.0;
    unsigned int i = (unsigned int)w;
    for (; i + 12 < cnt; i += 16) {
        const unsigned int v0 = pl[i], v1 = pl[i + 4], v2 = pl[i + 8], v3 = pl[i + 12];
        a0 += (double)xh[(size_t)v0 * HD + lane];
        a1 += (double)xh[(size_t)v1 * HD + lane];
        a2 += (double)xh[(size_t)v2 * HD + lane];
        a3 += (double)xh[(size_t)v3 * HD + lane];
    }
    for (; i < cnt; i += 4)
        a0 += (double)xh[(size_t)pl[i] * HD + lane];
    const double part = ((a0 + a1) + a2) + a3;

    if (w) sred[w - 1][lane] = part;
    __syncthreads();
    if (w == 0) {
        const double acc = ((part + sred[0][lane]) + sred[1][lane]) + sred[2][lane];
        const float esum = (float)acc;
        const float kv   = ke[(size_t)pair * D + lane];
        const float ov   = ko[0] ? (kv + DECAYF * (esum - kv)) : kv;
        outk[(size_t)pair * D + lane] = ov;
    }
}

extern "C" void kernel_launch(void* const* d_in, const int* in_sizes, int n_in,
                              void* d_out, int out_size, void* d_ws, size_t ws_size,
                              hipStream_t stream) {
    const float* x  = (const float*)d_in[0];
    const float* ke = (const float*)d_in[1];
    const int*   ko = (const int*)d_in[2];

    float* out  = (float*)d_out;
    float* outq = out;                                   // 8,388,608 floats
    float* outi = out + (size_t)H * NPH * D;             // +131,072 floats
    float* outk = outi + (size_t)NPH * H;                // +1,048,576 floats

    // workspace layout
    float*          esq    = (float*)d_ws;                              // 16,384 f32
    unsigned short* keb2   = (unsigned short*)(esq + H * C);            // 1M u16 (swizzled)
    unsigned short* indw   = keb2 + (size_t)H * C * D;                  // 131,072 u16
    unsigned int*   counts = (unsigned int*)(indw + (size_t)H * NPH);   // 16,384 u32
    unsigned int*   offv   = counts + H * C;                            // 16,384 u32
    unsigned int*   curv   = offv + H * C;                              // 16,384 u32
    unsigned int*   perm   = curv + H * C;                              // 131,072 u32

    vq_prep_kernel<<<(H * C) / 256, 256, 0, stream>>>(ke, keb2, esq, counts);
    vq_main_kernel<<<512, 256, 0, stream>>>(x, keb2, ke, esq, outq, outi, indw, counts);
    vq_scan_kernel<<<H, 256, 0, stream>>>(counts, offv, curv);
    vq_scatter_kernel<<<512, 256, 0, stream>>>(indw, curv, perm);
    vq_reduce_kernel<<<H * C, 256, 0, stream>>>(x, ke, perm, counts, offv, ko, outk);
}